// Round 1
// baseline (982.069 us; speedup 1.0000x reference)
//
#include <hip/hip_runtime.h>

// Problem dims
#define BB   512
#define S1K  196
#define SELK 36
#define RD   1024
#define AD   512

typedef __attribute__((ext_vector_type(4))) float f32x4;
typedef __attribute__((ext_vector_type(8))) short short8;

__device__ __forceinline__ unsigned short f2bf(float f) {
  unsigned u = __float_as_uint(f);
  u += 0x7fffu + ((u >> 16) & 1u);
  return (unsigned short)(u >> 16);
}
__device__ __forceinline__ float bf2f(unsigned short h) {
  return __uint_as_float(((unsigned)h) << 16);
}
__device__ __forceinline__ float fast_tanh(float x) {
  float e = __expf(2.f * x);
  return 1.f - 2.f / (e + 1.f);          // robust at +/- inf
}
__device__ __forceinline__ float fast_sigmoid(float x) {
  return 1.f / (1.f + __expf(-x));
}

// ---------------------------------------------------------------------------
// Generic C[M,N] = A[M,K] @ Bw[N,K]^T   (both row-major, K contiguous)
// bf16 MFMA, f32 accumulate. SPLIT==3 -> hi/lo split-bf16 (~fp32 accuracy).
// BETA==1 -> C += . NGUARD==1 -> guard B rows / C cols against N.
// Block: 256 threads (4 waves, 2x2 of 64x64). Tile 128x128, BK=32.
// ---------------------------------------------------------------------------
template<int SPLIT, int BETA, int NGUARD>
__global__ __launch_bounds__(256) void gemm_bt(
    const float* __restrict__ A, int lda,
    const float* __restrict__ Bw, int ldb,
    float* __restrict__ C, int ldc,
    int N, int K)
{
  __shared__ unsigned short Ah[128][40];
  __shared__ unsigned short Bh[128][40];
  __shared__ unsigned short Al[SPLIT == 3 ? 128 : 1][SPLIT == 3 ? 40 : 2];
  __shared__ unsigned short Bl[SPLIT == 3 ? 128 : 1][SPLIT == 3 ? 40 : 2];

  const int tid  = threadIdx.x;
  const int lane = tid & 63;
  const int wid  = tid >> 6;
  const int wm   = wid >> 1, wn = wid & 1;
  const int l16  = lane & 15, k8 = lane >> 4;

  const int r  = tid >> 1;          // staging row 0..127
  const int kh = (tid & 1) << 4;    // staging k-half 0/16

  const long arow = (long)blockIdx.x * 128 + r;
  const long brow = (long)blockIdx.y * 128 + r;
  const bool bok  = (!NGUARD) || (brow < N);
  const float* aP = A + arow * (long)lda + kh;
  const float* bP = Bw + (bok ? brow * (long)ldb + kh : 0);

  f32x4 acc[4][4];
#pragma unroll
  for (int i = 0; i < 4; i++)
#pragma unroll
    for (int j = 0; j < 4; j++) acc[i][j] = (f32x4){0.f, 0.f, 0.f, 0.f};

  for (int kt = 0; kt < K; kt += 32) {
    f32x4 a4[4], b4[4];
#pragma unroll
    for (int j = 0; j < 4; j++) a4[j] = *(const f32x4*)(aP + kt + j * 4);
#pragma unroll
    for (int j = 0; j < 4; j++)
      b4[j] = bok ? *(const f32x4*)(bP + kt + j * 4) : (f32x4){0.f, 0.f, 0.f, 0.f};

    __syncthreads();   // previous iteration's reads done

    short8 h0, h1;
#pragma unroll
    for (int j = 0; j < 8; j++) h0[j] = (short)f2bf(a4[j >> 2][j & 3]);
#pragma unroll
    for (int j = 0; j < 8; j++) { int q = j + 8; h1[j] = (short)f2bf(a4[q >> 2][q & 3]); }
    *(short8*)&Ah[r][kh]     = h0;
    *(short8*)&Ah[r][kh + 8] = h1;
    if (SPLIT == 3) {
      short8 l0, l1;
#pragma unroll
      for (int j = 0; j < 8; j++)
        l0[j] = (short)f2bf(a4[j >> 2][j & 3] - bf2f((unsigned short)h0[j]));
#pragma unroll
      for (int j = 0; j < 8; j++) { int q = j + 8;
        l1[j] = (short)f2bf(a4[q >> 2][q & 3] - bf2f((unsigned short)h1[j])); }
      *(short8*)&Al[r][kh]     = l0;
      *(short8*)&Al[r][kh + 8] = l1;
    }
#pragma unroll
    for (int j = 0; j < 8; j++) h0[j] = (short)f2bf(b4[j >> 2][j & 3]);
#pragma unroll
    for (int j = 0; j < 8; j++) { int q = j + 8; h1[j] = (short)f2bf(b4[q >> 2][q & 3]); }
    *(short8*)&Bh[r][kh]     = h0;
    *(short8*)&Bh[r][kh + 8] = h1;
    if (SPLIT == 3) {
      short8 l0, l1;
#pragma unroll
      for (int j = 0; j < 8; j++)
        l0[j] = (short)f2bf(b4[j >> 2][j & 3] - bf2f((unsigned short)h0[j]));
#pragma unroll
      for (int j = 0; j < 8; j++) { int q = j + 8;
        l1[j] = (short)f2bf(b4[q >> 2][q & 3] - bf2f((unsigned short)h1[j])); }
      *(short8*)&Bl[r][kh]     = l0;
      *(short8*)&Bl[r][kh + 8] = l1;
    }

    __syncthreads();

    short8 afh[4], bfh[4];
#pragma unroll
    for (int m = 0; m < 4; m++) afh[m] = *(const short8*)&Ah[wm * 64 + m * 16 + l16][k8 * 8];
#pragma unroll
    for (int n = 0; n < 4; n++) bfh[n] = *(const short8*)&Bh[wn * 64 + n * 16 + l16][k8 * 8];
#pragma unroll
    for (int m = 0; m < 4; m++)
#pragma unroll
      for (int n = 0; n < 4; n++)
        acc[m][n] = __builtin_amdgcn_mfma_f32_16x16x32_bf16(afh[m], bfh[n], acc[m][n], 0, 0, 0);
    if (SPLIT == 3) {
      short8 afl[4], bfl[4];
#pragma unroll
      for (int m = 0; m < 4; m++) afl[m] = *(const short8*)&Al[wm * 64 + m * 16 + l16][k8 * 8];
#pragma unroll
      for (int n = 0; n < 4; n++) bfl[n] = *(const short8*)&Bl[wn * 64 + n * 16 + l16][k8 * 8];
#pragma unroll
      for (int m = 0; m < 4; m++)
#pragma unroll
        for (int n = 0; n < 4; n++)
          acc[m][n] = __builtin_amdgcn_mfma_f32_16x16x32_bf16(afh[m], bfl[n], acc[m][n], 0, 0, 0);
#pragma unroll
      for (int m = 0; m < 4; m++)
#pragma unroll
        for (int n = 0; n < 4; n++)
          acc[m][n] = __builtin_amdgcn_mfma_f32_16x16x32_bf16(afl[m], bfh[n], acc[m][n], 0, 0, 0);
    }
  }

#pragma unroll
  for (int m = 0; m < 4; m++)
#pragma unroll
    for (int n = 0; n < 4; n++) {
      const long row0 = (long)blockIdx.x * 128 + wm * 64 + m * 16 + (lane >> 4) * 4;
      const long col  = (long)blockIdx.y * 128 + wn * 64 + n * 16 + l16;
      if (!NGUARD || col < N) {
#pragma unroll
        for (int j = 0; j < 4; j++) {
          float* p = C + (row0 + j) * (long)ldc + col;
          if (BETA) *p += acc[m][n][j]; else *p = acc[m][n][j];
        }
      }
    }
}

// ---------------------------------------------------------------------------
__global__ __launch_bounds__(256) void pack_x1_kernel(
    const float* __restrict__ xt, const float* __restrict__ fc,
    const float* __restrict__ sh, float* __restrict__ X1, float* __restrict__ X2)
{
  int i = blockIdx.x * 256 + threadIdx.x;   // [0, 512*1024)
  int b = i >> 10, rr = i & 1023;
  float h1 = sh[512 * 1024 + i];            // state_h[1]
  size_t base = (size_t)b * 4096;
  X1[base + rr]        = h1;                // prev_h
  X1[base + 1024 + rr] = fc[i];
  X1[base + 2048 + rr] = xt[i];
  X1[base + 3072 + rr] = sh[i];             // state_h[0] (hidden for Whh)
  X2[base + 3072 + rr] = h1;                // lang hidden = state_h[1]
}

// g:[512,4096] gates (i,f,g,o). Writes h to hA,hB; c to cOut; optional copies.
__global__ __launch_bounds__(256) void lstm_act_kernel(
    const float* __restrict__ g, const float* __restrict__ bih,
    const float* __restrict__ bhh, const float* __restrict__ cin,
    float* __restrict__ hA, float* __restrict__ hB, float* __restrict__ cOut,
    float* __restrict__ x2slot, float* __restrict__ concslot)
{
  int i = blockIdx.x * 256 + threadIdx.x;   // [0, 512*1024)
  int b = i >> 10, rr = i & 1023;
  size_t gb = (size_t)b * 4096;
  float gi = g[gb + rr]        + bih[rr]        + bhh[rr];
  float gf = g[gb + 1024 + rr] + bih[1024 + rr] + bhh[1024 + rr];
  float gg = g[gb + 2048 + rr] + bih[2048 + rr] + bhh[2048 + rr];
  float go = g[gb + 3072 + rr] + bih[3072 + rr] + bhh[3072 + rr];
  float c  = cin[i];
  float c2 = fast_sigmoid(gf) * c + fast_sigmoid(gi) * fast_tanh(gg);
  float h2 = fast_sigmoid(go) * fast_tanh(c2);
  hA[i] = h2;
  hB[i] = h2;
  cOut[i] = c2;
  if (x2slot)   x2slot[(size_t)b * 4096 + rr]  = h2;
  if (concslot) concslot[(size_t)b * 2048 + rr] = h2;
}

// scores[row] = sum_a walpha[a]*tanh(pf[row,a] + atth[b,a] + bh[a] (+extra[a])) + balpha
// one wave per row; pf row length hardcoded 512
template<bool EXTRA>
__global__ __launch_bounds__(256) void score_kernel(
    const float* __restrict__ pf, const float* __restrict__ atth,
    const float* __restrict__ bh, const float* __restrict__ extra,
    const float* __restrict__ walpha, const float* __restrict__ balpha,
    float* __restrict__ out, int S, int nrows)
{
  int gw = blockIdx.x * 4 + (threadIdx.x >> 6);
  int lane = threadIdx.x & 63;
  if (gw >= nrows) return;
  int b = gw / S;
  const float* p  = pf + (size_t)gw * 512 + lane * 8;
  const float* ah = atth + (size_t)b * 512 + lane * 8;
  const float* bp = bh + lane * 8;
  const float* wp = walpha + lane * 8;
  const float* ep = EXTRA ? extra + lane * 8 : nullptr;
  float acc = 0.f;
#pragma unroll
  for (int u = 0; u < 2; u++) {
    f32x4 pv = *(const f32x4*)(p + u * 4);
    f32x4 av = *(const f32x4*)(ah + u * 4);
    f32x4 bv = *(const f32x4*)(bp + u * 4);
    f32x4 wv = *(const f32x4*)(wp + u * 4);
    f32x4 ev = EXTRA ? *(const f32x4*)(ep + u * 4) : (f32x4){0.f, 0.f, 0.f, 0.f};
#pragma unroll
    for (int j = 0; j < 4; j++) {
      float x = pv[j] + av[j] + bv[j] + ev[j];
      acc += fast_tanh(x) * wv[j];
    }
  }
#pragma unroll
  for (int off = 32; off; off >>= 1) acc += __shfl_xor(acc, off);
  if (lane == 0) out[gw] = acc + balpha[0];
}

// block per b: softmax(scores[b,:S]) then out[b,:] = sum_s w_s * feats[b,s,:]
__global__ __launch_bounds__(256) void attsum_kernel(
    const float* __restrict__ scores, const float* __restrict__ feats, int S,
    float* __restrict__ out1, int ld1, float* __restrict__ out2, int ld2)
{
  __shared__ float w[256];
  int b = blockIdx.x, t = threadIdx.x;
  float s0 = (t < S) ? scores[b * S + t] : -3.0e38f;
  w[t] = s0;
  __syncthreads();
  float mx = -3.0e38f;
  for (int i = 0; i < S; i++) mx = fmaxf(mx, w[i]);
  float sum = 0.f;
  for (int i = 0; i < S; i++) sum += __expf(w[i] - mx);
  float inv = 1.f / sum;
  __syncthreads();
  if (t < S) w[t] = __expf(s0 - mx) * inv;
  __syncthreads();
  float a0 = 0.f, a1 = 0.f, a2 = 0.f, a3 = 0.f;
  for (int s = 0; s < S; s++) {
    float ws = w[s];
    const float* f = feats + ((size_t)b * S + s) * 1024 + t;
    a0 += ws * f[0];
    a1 += ws * f[256];
    a2 += ws * f[512];
    a3 += ws * f[768];
  }
  out1[(size_t)b * ld1 + t]       = a0;
  out1[(size_t)b * ld1 + t + 256] = a1;
  out1[(size_t)b * ld1 + t + 512] = a2;
  out1[(size_t)b * ld1 + t + 768] = a3;
  if (out2) {
    out2[(size_t)b * ld2 + t]       = a0;
    out2[(size_t)b * ld2 + t + 256] = a1;
    out2[(size_t)b * ld2 + t + 512] = a2;
    out2[(size_t)b * ld2 + t + 768] = a3;
  }
}

// one wave per b: top-36 indices of vfha[b,:]+b_vf (order irrelevant downstream)
__global__ __launch_bounds__(64) void topk_kernel(
    const float* __restrict__ vfha, const float* __restrict__ b_vf, int* __restrict__ ix)
{
  int b = blockIdx.x;
  int lane = threadIdx.x;
  float v[4];
#pragma unroll
  for (int j = 0; j < 4; j++) {
    int s = lane + 64 * j;
    v[j] = (s < 196) ? (vfha[b * 196 + s] + b_vf[s]) : -3.0e38f;
  }
  for (int it = 0; it < 36; it++) {
    float bv = -3.0e38f; int bs = 1 << 20;
#pragma unroll
    for (int j = 0; j < 4; j++) {
      int s = lane + 64 * j;
      if (v[j] > bv) { bv = v[j]; bs = s; }
    }
#pragma unroll
    for (int off = 32; off; off >>= 1) {
      float ov = __shfl_xor(bv, off);
      int   os = __shfl_xor(bs, off);
      if (ov > bv || (ov == bv && os < bs)) { bv = ov; bs = os; }
    }
    if ((bs & 63) == lane) v[bs >> 6] = -3.0e38f;
    if (lane == 0) ix[b * 36 + it] = bs;
  }
}

// block per (b,j): arr1[b,j,:] = att_feats[b, ix[b,j], :]
__global__ __launch_bounds__(256) void gather_kernel(
    const float* __restrict__ feats, const int* __restrict__ ix, float* __restrict__ dst)
{
  int bj = blockIdx.x;
  int b = bj / 36;
  int s = ix[bj];
  const f32x4* src = (const f32x4*)(feats + ((size_t)b * 196 + s) * 1024);
  f32x4* d = (f32x4*)(dst + (size_t)bj * 1024);
  d[threadIdx.x] = src[threadIdx.x];
}

// ---------------------------------------------------------------------------
extern "C" void kernel_launch(void* const* d_in, const int* in_sizes, int n_in,
                              void* d_out, int out_size, void* d_ws, size_t ws_size,
                              hipStream_t stream) {
  const float* xt        = (const float*)d_in[0];
  const float* fc_feats  = (const float*)d_in[1];
  const float* att_feats = (const float*)d_in[2];
  const float* p_att     = (const float*)d_in[3];
  const float* state_h   = (const float*)d_in[4];
  const float* state_c   = (const float*)d_in[5];
  const float* W_ih_att  = (const float*)d_in[6];
  const float* b_ih_att  = (const float*)d_in[7];
  const float* W_hh_att  = (const float*)d_in[8];
  const float* b_hh_att  = (const float*)d_in[9];
  const float* W_ih_lang = (const float*)d_in[10];
  const float* b_ih_lang = (const float*)d_in[11];
  const float* W_hh_lang = (const float*)d_in[12];
  const float* b_hh_lang = (const float*)d_in[13];
  const float* Wh2att1   = (const float*)d_in[14];
  const float* bh2att1   = (const float*)d_in[15];
  const float* Walpha1   = (const float*)d_in[16];
  const float* balpha1   = (const float*)d_in[17];
  const float* Wh2att2   = (const float*)d_in[18];
  const float* bh2att2   = (const float*)d_in[19];
  const float* Walpha2   = (const float*)d_in[20];
  const float* balpha2   = (const float*)d_in[21];
  const float* W_vf      = (const float*)d_in[22];
  const float* b_vf      = (const float*)d_in[23];
  const float* W_pvf     = (const float*)d_in[24];
  const float* b_pvf     = (const float*)d_in[25];

  float* out = (float*)d_out;
  float* ws  = (float*)d_ws;

  float* X1      = ws;                        // [512,4096]
  float* X2      = X1 + 512 * 4096;           // [512,4096]
  float* g1      = X2 + 512 * 4096;           // [512,4096]
  float* g2      = g1 + 512 * 4096;           // [512,4096]
  float* hatt    = g2 + 512 * 4096;           // [512,1024]
  float* atth1   = hatt + 512 * 1024;         // [512,512]
  float* atth2   = atth1 + 512 * 512;         // [512,512]
  float* scores1 = atth2 + 512 * 512;         // [512,196]
  float* conc    = scores1 + 512 * 196;       // [512,2048]
  float* vfha    = conc + 512 * 2048;         // [512,196]
  int*   vfix    = (int*)(vfha + 512 * 196);  // [512,36]
  float* arr1    = vfha + 512 * 196 + 512 * 36; // [512,36,1024]
  float* pvf     = arr1 + 512 * 36 * 1024;    // [512,36,512]
  float* scores2 = pvf + 512 * 36 * 512;      // [512,36]

  float* out_h0 = out + 512 * 1024;
  float* out_h1 = out + 2 * 512 * 1024;
  float* out_c0 = out + 3 * 512 * 1024;
  float* out_c1 = out + 4 * 512 * 1024;

  // 1. pack X1 (and X2's state_h[1] slot)
  pack_x1_kernel<<<2048, 256, 0, stream>>>(xt, fc_feats, state_h, X1, X2);

  // 2-3. att-LSTM gates (split-bf16 for accuracy: feeds top-k path)
  gemm_bt<3, 0, 0><<<dim3(4, 32), 256, 0, stream>>>(X1, 4096, W_ih_att, 3072, g1, 4096, 4096, 3072);
  gemm_bt<3, 1, 0><<<dim3(4, 32), 256, 0, stream>>>(X1 + 3072, 4096, W_hh_att, 1024, g1, 4096, 4096, 1024);

  // 4. att-LSTM activation -> h_att, c_att
  lstm_act_kernel<<<2048, 256, 0, stream>>>(g1, b_ih_att, b_hh_att, state_c,
                                            hatt, out_h0, out_c0, X2 + 1024, conc + 1024);

  // 5-6. att_h projections for both attentions
  gemm_bt<1, 0, 0><<<dim3(4, 4), 256, 0, stream>>>(hatt, 1024, Wh2att1, 1024, atth1, 512, 512, 1024);
  gemm_bt<1, 0, 0><<<dim3(4, 4), 256, 0, stream>>>(hatt, 1024, Wh2att2, 1024, atth2, 512, 512, 1024);

  // 7. attention-1 scores (reads p_att_feats, 205 MB)
  score_kernel<false><<<25088, 256, 0, stream>>>(p_att, atth1, bh2att1, nullptr,
                                                 Walpha1, balpha1, scores1, 196, 512 * 196);

  // 8. attention-1 softmax + weighted sum (reads att_feats, 411 MB)
  attsum_kernel<<<512, 256, 0, stream>>>(scores1, att_feats, 196, conc, 2048, X2 + 2048, 4096);

  // 9. vf logits (split-bf16: feeds top-k)
  gemm_bt<3, 0, 1><<<dim3(4, 2), 256, 0, stream>>>(conc, 2048, W_vf, 2048, vfha, 196, 196, 2048);

  // 10. top-36 selection
  topk_kernel<<<512, 64, 0, stream>>>(vfha, b_vf, vfix);

  // 11. gather selected feature rows
  gather_kernel<<<18432, 256, 0, stream>>>(att_feats, vfix, arr1);

  // 12. p_vf_feats = arr1 @ W_pvf^T
  gemm_bt<1, 0, 0><<<dim3(144, 4), 256, 0, stream>>>(arr1, 1024, W_pvf, 1024, pvf, 512, 512, 1024);

  // 13. attention-2 scores (includes b_pvf and bh2att2)
  score_kernel<true><<<4608, 256, 0, stream>>>(pvf, atth2, bh2att2, b_pvf,
                                               Walpha2, balpha2, scores2, 36, 512 * 36);

  // 14. attention-2 softmax + weighted sum -> X2[:,0:1024]
  attsum_kernel<<<512, 256, 0, stream>>>(scores2, arr1, 36, X2, 4096, nullptr, 0);

  // 15-16. lang-LSTM gates
  gemm_bt<1, 0, 0><<<dim3(4, 32), 256, 0, stream>>>(X2, 4096, W_ih_lang, 3072, g2, 4096, 4096, 3072);
  gemm_bt<1, 1, 0><<<dim3(4, 32), 256, 0, stream>>>(X2 + 3072, 4096, W_hh_lang, 1024, g2, 4096, 4096, 1024);

  // 17. lang-LSTM activation -> output, new_h[1], new_c[1]
  lstm_act_kernel<<<2048, 256, 0, stream>>>(g2, b_ih_lang, b_hh_lang, state_c + 512 * 1024,
                                            out, out_h1, out_c1, nullptr, nullptr);
}

// Round 2
// 572.981 us; speedup vs baseline: 1.7140x; 1.7140x over previous
//
#include <hip/hip_runtime.h>

typedef __attribute__((ext_vector_type(4))) float f32x4;
typedef __attribute__((ext_vector_type(8))) _Float16 half8;
typedef __attribute__((ext_vector_type(4))) _Float16 half4;

__device__ __forceinline__ float fast_tanh(float x) {
  float e = __expf(2.f * x);
  return 1.f - 2.f / (e + 1.f);
}
__device__ __forceinline__ float fast_sigmoid(float x) {
  return 1.f / (1.f + __expf(-x));
}

__device__ __forceinline__ void gl_lds16(const _Float16* g, _Float16* l) {
  __builtin_amdgcn_global_load_lds(
      (const __attribute__((address_space(1))) void*)g,
      (__attribute__((address_space(3))) void*)l, 16, 0, 0);
}

// ---------------------------------------------------------------------------
// C[M,N] = A[M,K] @ B[N,K]^T, fp16 inputs (hi/lo split optional), f32 accum.
// m97 structure: 128x128 tile, BK=32, 4 waves, global_load_lds(16B), linear LDS.
// gridDim.z = K-split; each z writes C + z*czstride (partials summed later).
// ---------------------------------------------------------------------------
template<int SPLIT, int OUT16, int NGUARD>
__global__ __launch_bounds__(256) void gemm16(
    const _Float16* __restrict__ Ahp, const _Float16* __restrict__ Alp, int lda,
    const _Float16* __restrict__ Bhp, const _Float16* __restrict__ Blp, int ldb,
    void* __restrict__ Cp, int ldc, long czstride,
    int N, int Kc)
{
  __shared__ _Float16 sAh[128 * 32];
  __shared__ _Float16 sBh[128 * 32];
  __shared__ _Float16 sAl[SPLIT == 3 ? 128 * 32 : 8];
  __shared__ _Float16 sBl[SPLIT == 3 ? 128 * 32 : 8];

  const int tid = threadIdx.x, lane = tid & 63, wid = tid >> 6;
  const int wm = wid >> 1, wn = wid & 1;
  const int l16 = lane & 15, k8 = lane >> 4;
  const int srow = lane >> 2;          // 0..15 within a 16-row chunk
  const int scol = (lane & 3) * 8;     // fp16 col offset (16B granules)

  const int  kt0   = blockIdx.z * Kc;
  const long abase = (long)blockIdx.x * 128;
  const long bbase = (long)blockIdx.y * 128;

  const int r0 = wid * 32 + srow;       // this wave's staging rows
  const int r1 = wid * 32 + 16 + srow;
  long br0 = bbase + r0, br1 = bbase + r1;
  if (NGUARD) {
    if (br0 > N - 1) br0 = N - 1;
    if (br1 > N - 1) br1 = N - 1;
  }

  const _Float16* ga0 = Ahp + (abase + r0) * (long)lda + kt0 + scol;
  const _Float16* ga1 = Ahp + (abase + r1) * (long)lda + kt0 + scol;
  const _Float16* gb0 = Bhp + br0 * (long)ldb + kt0 + scol;
  const _Float16* gb1 = Bhp + br1 * (long)ldb + kt0 + scol;
  const _Float16* la0 = SPLIT == 3 ? Alp + (abase + r0) * (long)lda + kt0 + scol : nullptr;
  const _Float16* la1 = SPLIT == 3 ? Alp + (abase + r1) * (long)lda + kt0 + scol : nullptr;
  const _Float16* lb0 = SPLIT == 3 ? Blp + br0 * (long)ldb + kt0 + scol : nullptr;
  const _Float16* lb1 = SPLIT == 3 ? Blp + br1 * (long)ldb + kt0 + scol : nullptr;

  const int e0 = (wid * 32) * 32;        // lds elem base, chunk 0 (wave-uniform)
  const int e1 = (wid * 32 + 16) * 32;   // chunk 1

  f32x4 acc[4][4];
#pragma unroll
  for (int i = 0; i < 4; i++)
#pragma unroll
    for (int j = 0; j < 4; j++) acc[i][j] = (f32x4){0.f, 0.f, 0.f, 0.f};

  for (int kk = 0; kk < Kc; kk += 32) {
    gl_lds16(ga0 + kk, sAh + e0);
    gl_lds16(ga1 + kk, sAh + e1);
    gl_lds16(gb0 + kk, sBh + e0);
    gl_lds16(gb1 + kk, sBh + e1);
    if (SPLIT == 3) {
      gl_lds16(la0 + kk, sAl + e0);
      gl_lds16(la1 + kk, sAl + e1);
      gl_lds16(lb0 + kk, sBl + e0);
      gl_lds16(lb1 + kk, sBl + e1);
    }
    __syncthreads();

    half8 ah[4], bh[4];
#pragma unroll
    for (int m = 0; m < 4; m++)
      ah[m] = *(const half8*)&sAh[(wm * 64 + m * 16 + l16) * 32 + k8 * 8];
#pragma unroll
    for (int n = 0; n < 4; n++)
      bh[n] = *(const half8*)&sBh[(wn * 64 + n * 16 + l16) * 32 + k8 * 8];
#pragma unroll
    for (int m = 0; m < 4; m++)
#pragma unroll
      for (int n = 0; n < 4; n++)
        acc[m][n] = __builtin_amdgcn_mfma_f32_16x16x32_f16(ah[m], bh[n], acc[m][n], 0, 0, 0);
    if (SPLIT == 3) {
      half8 al[4], bl[4];
#pragma unroll
      for (int m = 0; m < 4; m++)
        al[m] = *(const half8*)&sAl[(wm * 64 + m * 16 + l16) * 32 + k8 * 8];
#pragma unroll
      for (int n = 0; n < 4; n++)
        bl[n] = *(const half8*)&sBl[(wn * 64 + n * 16 + l16) * 32 + k8 * 8];
#pragma unroll
      for (int m = 0; m < 4; m++)
#pragma unroll
        for (int n = 0; n < 4; n++) {
          acc[m][n] = __builtin_amdgcn_mfma_f32_16x16x32_f16(al[m], bh[n], acc[m][n], 0, 0, 0);
          acc[m][n] = __builtin_amdgcn_mfma_f32_16x16x32_f16(ah[m], bl[n], acc[m][n], 0, 0, 0);
        }
    }
    __syncthreads();
  }

  const long czoff = (long)blockIdx.z * czstride;
#pragma unroll
  for (int m = 0; m < 4; m++)
#pragma unroll
    for (int n = 0; n < 4; n++) {
      const long row0 = abase + wm * 64 + m * 16 + (lane >> 4) * 4;
      const long col  = bbase + wn * 64 + n * 16 + l16;
      if (!NGUARD || col < N) {
#pragma unroll
        for (int j = 0; j < 4; j++) {
          if (OUT16) ((_Float16*)Cp)[(row0 + j) * (long)ldc + col + czoff] = (_Float16)acc[m][n][j];
          else       ((float*)Cp)[(row0 + j) * (long)ldc + col + czoff] = acc[m][n][j];
        }
      }
    }
}

// ---------------------------------------------------------------------------
// pack X1 (hi/lo fp16) and X2 state_h[1] slot
__global__ __launch_bounds__(256) void pack_kernel(
    const float* __restrict__ xt, const float* __restrict__ fc,
    const float* __restrict__ sh,
    _Float16* __restrict__ X1h, _Float16* __restrict__ X1l, _Float16* __restrict__ X2h)
{
  int i = blockIdx.x * 256 + threadIdx.x;   // [0, 512*1024)
  int b = i >> 10, rr = i & 1023;
  long base = (long)b * 4096;
  float v[4];
  v[0] = sh[524288 + i];   // prev_h = state_h[1]
  v[1] = fc[i];
  v[2] = xt[i];
  v[3] = sh[i];            // state_h[0] (hidden)
#pragma unroll
  for (int j = 0; j < 4; j++) {
    _Float16 h = (_Float16)v[j];
    X1h[base + j * 1024 + rr] = h;
    X1l[base + j * 1024 + rr] = (_Float16)(v[j] - (float)h);
  }
  X2h[base + 3072 + rr] = (_Float16)v[0];   // lang hidden = state_h[1]
}

// convert weights (all but lang): Wc_att hi/lo, Whh12, Wvf hi/lo, Wpvf
__global__ __launch_bounds__(256) void convertA_kernel(
    const float* __restrict__ WihA, const float* __restrict__ WhhA,
    const float* __restrict__ Wh1, const float* __restrict__ Wh2,
    const float* __restrict__ Wvf, const float* __restrict__ Wpvf,
    _Float16* __restrict__ WcAh, _Float16* __restrict__ WcAl,
    _Float16* __restrict__ W12h, _Float16* __restrict__ Wvfh,
    _Float16* __restrict__ Wvfl, _Float16* __restrict__ Wpvfh)
{
  int bi = blockIdx.x, t = threadIdx.x;
  if (bi < 16384) {                       // Wc_att [4096][4096] hi+lo
    long e = ((long)bi * 256 + t) * 4;
    int row = (int)(e >> 12), col = (int)(e & 4095);
    const float* src = (col < 3072) ? WihA + (long)row * 3072 + col
                                    : WhhA + (long)row * 1024 + (col - 3072);
    f32x4 v = *(const f32x4*)src;
    half4 h, l;
#pragma unroll
    for (int j = 0; j < 4; j++) { h[j] = (_Float16)v[j]; l[j] = (_Float16)(v[j] - (float)h[j]); }
    *(half4*)&WcAh[e] = h;
    *(half4*)&WcAl[e] = l;
  } else if (bi < 17408) {                // Whh12 [1024][1024]
    long e = ((long)(bi - 16384) * 256 + t) * 4;
    int row = (int)(e >> 10), col = (int)(e & 1023);
    const float* src = (row < 512) ? Wh1 + (long)row * 1024 + col
                                   : Wh2 + (long)(row - 512) * 1024 + col;
    f32x4 v = *(const f32x4*)src;
    half4 h;
#pragma unroll
    for (int j = 0; j < 4; j++) h[j] = (_Float16)v[j];
    *(half4*)&W12h[e] = h;
  } else if (bi < 17800) {                // Wvf [196][2048] hi+lo (linear)
    long e = ((long)(bi - 17408) * 256 + t) * 4;
    f32x4 v = *(const f32x4*)(Wvf + e);
    half4 h, l;
#pragma unroll
    for (int j = 0; j < 4; j++) { h[j] = (_Float16)v[j]; l[j] = (_Float16)(v[j] - (float)h[j]); }
    *(half4*)&Wvfh[e] = h;
    *(half4*)&Wvfl[e] = l;
  } else {                                // Wpvf [512][1024] (linear)
    long e = ((long)(bi - 17800) * 256 + t) * 4;
    f32x4 v = *(const f32x4*)(Wpvf + e);
    half4 h;
#pragma unroll
    for (int j = 0; j < 4; j++) h[j] = (_Float16)v[j];
    *(half4*)&Wpvfh[e] = h;
  }
}

// convert lang weights (after att GEMM; overlays Wc_att_hi region)
__global__ __launch_bounds__(256) void convertL_kernel(
    const float* __restrict__ WihL, const float* __restrict__ WhhL,
    _Float16* __restrict__ WcLh)
{
  long e = ((long)blockIdx.x * 256 + threadIdx.x) * 4;
  int row = (int)(e >> 12), col = (int)(e & 4095);
  const float* src = (col < 3072) ? WihL + (long)row * 3072 + col
                                  : WhhL + (long)row * 1024 + (col - 3072);
  f32x4 v = *(const f32x4*)src;
  half4 h;
#pragma unroll
  for (int j = 0; j < 4; j++) h[j] = (_Float16)v[j];
  *(half4*)&WcLh[e] = h;
}

// LSTM activation; g = gp[0] + gp[1] + biases (K-split partials)
template<bool ATT>
__global__ __launch_bounds__(256) void lstm_act_kernel(
    const float* __restrict__ g, const float* __restrict__ bih,
    const float* __restrict__ bhh, const float* __restrict__ cin,
    float* __restrict__ hOut, float* __restrict__ cOut,
    _Float16* __restrict__ hatt_h, _Float16* __restrict__ conch,
    _Float16* __restrict__ concl, _Float16* __restrict__ x2h,
    float* __restrict__ hOut2)
{
  const long S = 2097152;   // 512*4096
  int i = blockIdx.x * 256 + threadIdx.x;   // [0, 512*1024)
  int b = i >> 10, rr = i & 1023;
  long gb = (long)b * 4096;
  float gi = g[gb + rr]        + g[S + gb + rr]        + bih[rr]        + bhh[rr];
  float gf = g[gb + 1024 + rr] + g[S + gb + 1024 + rr] + bih[1024 + rr] + bhh[1024 + rr];
  float gg = g[gb + 2048 + rr] + g[S + gb + 2048 + rr] + bih[2048 + rr] + bhh[2048 + rr];
  float go = g[gb + 3072 + rr] + g[S + gb + 3072 + rr] + bih[3072 + rr] + bhh[3072 + rr];
  float c  = cin[i];
  float c2 = fast_sigmoid(gf) * c + fast_sigmoid(gi) * fast_tanh(gg);
  float h2 = fast_sigmoid(go) * fast_tanh(c2);
  hOut[i] = h2;
  cOut[i] = c2;
  if (hOut2) hOut2[i] = h2;
  if (ATT) {
    _Float16 hh = (_Float16)h2;
    hatt_h[i] = hh;
    conch[(long)b * 2048 + 1024 + rr] = hh;
    concl[(long)b * 2048 + 1024 + rr] = (_Float16)(h2 - (float)hh);
    x2h[(long)b * 4096 + 1024 + rr] = hh;
  }
}

// scores[row] = sum_a walpha[a]*tanh(pf[row,a] + atth[b,a] + bh[a] (+extra[a])) + balpha
template<bool EXTRA, bool PF16>
__global__ __launch_bounds__(256) void score_kernel(
    const void* __restrict__ pf, const float* __restrict__ atth,
    const float* __restrict__ bh, const float* __restrict__ extra,
    const float* __restrict__ walpha, const float* __restrict__ balpha,
    float* __restrict__ out, int S, int nrows)
{
  int gw = blockIdx.x * 4 + (threadIdx.x >> 6);
  int lane = threadIdx.x & 63;
  if (gw >= nrows) return;
  int b = gw / S;
  const float* ah = atth + (long)b * 1024 + lane * 8;
  const float* bp = bh + lane * 8;
  const float* wp = walpha + lane * 8;
  const float* ep = EXTRA ? extra + lane * 8 : nullptr;
  float pv[8];
  if (PF16) {
    half8 hv = *(const half8*)((const _Float16*)pf + (long)gw * 512 + lane * 8);
#pragma unroll
    for (int j = 0; j < 8; j++) pv[j] = (float)hv[j];
  } else {
    const float* p = (const float*)pf + (long)gw * 512 + lane * 8;
#pragma unroll
    for (int u = 0; u < 2; u++) { f32x4 t = *(const f32x4*)(p + u * 4);
#pragma unroll
      for (int j = 0; j < 4; j++) pv[u * 4 + j] = t[j]; }
  }
  float acc = 0.f;
#pragma unroll
  for (int u = 0; u < 2; u++) {
    f32x4 av = *(const f32x4*)(ah + u * 4);
    f32x4 bv = *(const f32x4*)(bp + u * 4);
    f32x4 wv = *(const f32x4*)(wp + u * 4);
    f32x4 ev = EXTRA ? *(const f32x4*)(ep + u * 4) : (f32x4){0.f, 0.f, 0.f, 0.f};
#pragma unroll
    for (int j = 0; j < 4; j++) {
      float x = pv[u * 4 + j] + av[j] + bv[j] + ev[j];
      acc += fast_tanh(x) * wv[j];
    }
  }
#pragma unroll
  for (int off = 32; off; off >>= 1) acc += __shfl_xor(acc, off);
  if (lane == 0) out[gw] = acc + balpha[0];
}

// softmax(scores[b,:196]) then weighted sum of att_feats -> conc hi/lo + X2h slot
__global__ __launch_bounds__(256) void attsum1_kernel(
    const float* __restrict__ scores, const float* __restrict__ feats,
    _Float16* __restrict__ conch, _Float16* __restrict__ concl, _Float16* __restrict__ x2h)
{
  __shared__ float w[256];
  int b = blockIdx.x, t = threadIdx.x;
  float s0 = (t < 196) ? scores[b * 196 + t] : -3.0e38f;
  w[t] = s0;
  __syncthreads();
  float mx = -3.0e38f;
  for (int i = 0; i < 196; i++) mx = fmaxf(mx, w[i]);
  float sum = 0.f;
  for (int i = 0; i < 196; i++) sum += __expf(w[i] - mx);
  float inv = 1.f / sum;
  __syncthreads();
  if (t < 196) w[t] = __expf(s0 - mx) * inv;
  __syncthreads();
  f32x4 acc = (f32x4){0.f, 0.f, 0.f, 0.f};
  const float* fb = feats + (long)b * 196 * 1024 + t * 4;
#pragma unroll 4
  for (int s = 0; s < 196; s++) {
    float ws = w[s];
    f32x4 v = *(const f32x4*)(fb + (long)s * 1024);
#pragma unroll
    for (int j = 0; j < 4; j++) acc[j] += ws * v[j];
  }
  half4 h, l;
#pragma unroll
  for (int j = 0; j < 4; j++) { h[j] = (_Float16)acc[j]; l[j] = (_Float16)(acc[j] - (float)h[j]); }
  *(half4*)&conch[(long)b * 2048 + t * 4] = h;
  *(half4*)&concl[(long)b * 2048 + t * 4] = l;
  *(half4*)&x2h[(long)b * 4096 + 2048 + t * 4] = h;
}

// softmax(scores2[b,:36]) then weighted sum of arr1h (fp16) -> X2h[:,0:1024]
__global__ __launch_bounds__(256) void attsum2_kernel(
    const float* __restrict__ scores, const _Float16* __restrict__ arr1h,
    _Float16* __restrict__ x2h)
{
  __shared__ float w[64];
  int b = blockIdx.x, t = threadIdx.x;
  if (t < 64) w[t] = (t < 36) ? scores[b * 36 + t] : -3.0e38f;
  __syncthreads();
  float mx = -3.0e38f;
  for (int i = 0; i < 36; i++) mx = fmaxf(mx, w[i]);
  float sum = 0.f;
  for (int i = 0; i < 36; i++) sum += __expf(w[i] - mx);
  float inv = 1.f / sum;
  __syncthreads();
  if (t < 36) w[t] = __expf(w[t] - mx) * inv;
  __syncthreads();
  f32x4 acc = (f32x4){0.f, 0.f, 0.f, 0.f};
  const _Float16* fb = arr1h + (long)b * 36 * 1024 + t * 4;
#pragma unroll 4
  for (int s = 0; s < 36; s++) {
    float ws = w[s];
    half4 v = *(const half4*)(fb + (long)s * 1024);
#pragma unroll
    for (int j = 0; j < 4; j++) acc[j] += ws * (float)v[j];
  }
  half4 h;
#pragma unroll
  for (int j = 0; j < 4; j++) h[j] = (_Float16)acc[j];
  *(half4*)&x2h[(long)b * 4096 + t * 4] = h;
}

// one wave per b: top-36 indices (set only; order irrelevant downstream)
__global__ __launch_bounds__(64) void topk_kernel(
    const float* __restrict__ vfha, const float* __restrict__ b_vf, int* __restrict__ ix)
{
  int b = blockIdx.x;
  int lane = threadIdx.x;
  float v[4];
#pragma unroll
  for (int j = 0; j < 4; j++) {
    int s = lane + 64 * j;
    v[j] = (s < 196) ? (vfha[b * 196 + s] + b_vf[s]) : -3.0e38f;
  }
  for (int it = 0; it < 36; it++) {
    float bv = -3.0e38f; int bs = 1 << 20;
#pragma unroll
    for (int j = 0; j < 4; j++) {
      int s = lane + 64 * j;
      if (v[j] > bv) { bv = v[j]; bs = s; }
    }
#pragma unroll
    for (int off = 32; off; off >>= 1) {
      float ov = __shfl_xor(bv, off);
      int   os = __shfl_xor(bs, off);
      if (ov > bv || (ov == bv && os < bs)) { bv = ov; bs = os; }
    }
    if ((bs & 63) == lane) v[bs >> 6] = -3.0e38f;
    if (lane == 0) ix[b * 36 + it] = bs;
  }
}

// gather + fp16 convert: arr1h[bj,:] = fp16(att_feats[b, ix[bj], :])
__global__ __launch_bounds__(256) void gather_conv_kernel(
    const float* __restrict__ feats, const int* __restrict__ ix, _Float16* __restrict__ dst)
{
  int bj = blockIdx.x;
  int b = bj / 36;
  int s = ix[bj];
  int t = threadIdx.x;
  f32x4 v = *(const f32x4*)(feats + ((long)b * 196 + s) * 1024 + t * 4);
  half4 h;
#pragma unroll
  for (int j = 0; j < 4; j++) h[j] = (_Float16)v[j];
  *(half4*)&dst[(long)bj * 1024 + t * 4] = h;
}

// ---------------------------------------------------------------------------
extern "C" void kernel_launch(void* const* d_in, const int* in_sizes, int n_in,
                              void* d_out, int out_size, void* d_ws, size_t ws_size,
                              hipStream_t stream) {
  const float* xt        = (const float*)d_in[0];
  const float* fc_feats  = (const float*)d_in[1];
  const float* att_feats = (const float*)d_in[2];
  const float* p_att     = (const float*)d_in[3];
  const float* state_h   = (const float*)d_in[4];
  const float* state_c   = (const float*)d_in[5];
  const float* b_ih_att  = (const float*)d_in[7];
  const float* b_hh_att  = (const float*)d_in[9];
  const float* b_ih_lang = (const float*)d_in[11];
  const float* b_hh_lang = (const float*)d_in[13];
  const float* bh2att1   = (const float*)d_in[15];
  const float* Walpha1   = (const float*)d_in[16];
  const float* balpha1   = (const float*)d_in[17];
  const float* bh2att2   = (const float*)d_in[19];
  const float* Walpha2   = (const float*)d_in[20];
  const float* balpha2   = (const float*)d_in[21];
  const float* b_vf      = (const float*)d_in[23];
  const float* b_pvf     = (const float*)d_in[25];

  float* out = (float*)d_out;
  float* W = (float*)d_ws;   // pool, f32-unit offsets

  _Float16* WcAh   = (_Float16*)(W + 0);         // [4096][4096] hi -> later WcLh
  _Float16* WcAl   = (_Float16*)(W + 8388608);   // [4096][4096] lo -> later arr1h/g2p
  _Float16* X1h    = (_Float16*)(W + 16777216);  // [512][4096]
  _Float16* X1l    = (_Float16*)(W + 18874368);
  float*    g1p    = W + 20971520;               // [2][512][4096] -> later pvf16
  _Float16* hatt_h = (_Float16*)(W + 25165824);  // [512][1024] (clobbered by pvf16 later)
  _Float16* W12h   = (_Float16*)(W + 25690112);  // [1024][1024]
  _Float16* Wvfh   = (_Float16*)(W + 26214400);  // [196][2048]
  _Float16* Wvfl   = (_Float16*)(W + 26415104);
  _Float16* Wpvfh  = (_Float16*)(W + 26615808);  // [512][1024]
  float*    atth   = W + 26877952;               // [512][1024] f32
  _Float16* conch  = (_Float16*)(W + 27402240);  // [512][2048]
  _Float16* concl  = (_Float16*)(W + 27926528);
  _Float16* X2h    = (_Float16*)(W + 28450816);  // [512][4096]
  float*    scores1= W + 29499392;               // [512*196]
  float*    vfha   = W + 29599744;               // [512*196]
  int*      vfix   = (int*)(W + 29700096);       // [512*36]
  float*    scores2= W + 29718528;               // [512*36]
  // overlays (after producers are dead):
  _Float16* WcLh   = WcAh;                        // lang weights (after att gemm)
  _Float16* arr1h  = (_Float16*)(W + 8388608);    // [18432][1024] fp16 (after att gemm)
  float*    g2p    = W + 8388608;                 // [2][512][4096] (after attsum2)
  _Float16* pvf16  = (_Float16*)(W + 20971520);   // [18432][512] fp16 (after atth gemm)

  float* out_h0 = out + 524288;
  float* out_h1 = out + 2 * 524288;
  float* out_c0 = out + 3 * 524288;
  float* out_c1 = out + 4 * 524288;

  // 1. pack X1 hi/lo + X2 state slot
  pack_kernel<<<2048, 256, 0, stream>>>(xt, fc_feats, state_h, X1h, X1l, X2h);

  // 2. convert all weights except lang
  convertA_kernel<<<18312, 256, 0, stream>>>(
      (const float*)d_in[6], (const float*)d_in[8],
      (const float*)d_in[14], (const float*)d_in[18],
      (const float*)d_in[22], (const float*)d_in[24],
      WcAh, WcAl, W12h, Wvfh, Wvfl, Wpvfh);

  // 3. att-LSTM gates, 3-term split fp16, K-split z=2
  gemm16<3, 0, 0><<<dim3(4, 32, 2), 256, 0, stream>>>(
      X1h, X1l, 4096, WcAh, WcAl, 4096, g1p, 4096, 2097152, 4096, 2048);

  // 4. att-LSTM activation
  lstm_act_kernel<true><<<2048, 256, 0, stream>>>(
      g1p, b_ih_att, b_hh_att, state_c, out_h0, out_c0,
      hatt_h, conch, concl, X2h, nullptr);

  // 5. convert lang weights (overlay onto WcAh region)
  convertL_kernel<<<16384, 256, 0, stream>>>(
      (const float*)d_in[10], (const float*)d_in[12], WcLh);

  // 6. fused atth1|atth2 projection
  gemm16<1, 0, 0><<<dim3(4, 8, 1), 256, 0, stream>>>(
      hatt_h, nullptr, 1024, W12h, nullptr, 1024, atth, 1024, 0, 1024, 1024);

  // 7. attention-1 scores
  score_kernel<false, false><<<25088, 256, 0, stream>>>(
      p_att, atth, bh2att1, nullptr, Walpha1, balpha1, scores1, 196, 100352);

  // 8. attention-1 softmax + weighted sum
  attsum1_kernel<<<512, 256, 0, stream>>>(scores1, att_feats, conch, concl, X2h);

  // 9. vf logits (3-term split)
  gemm16<3, 0, 1><<<dim3(4, 2, 1), 256, 0, stream>>>(
      conch, concl, 2048, Wvfh, Wvfl, 2048, vfha, 196, 0, 196, 2048);

  // 10. top-36
  topk_kernel<<<512, 64, 0, stream>>>(vfha, b_vf, vfix);

  // 11. gather + fp16 convert
  gather_conv_kernel<<<18432, 256, 0, stream>>>(att_feats, vfix, arr1h);

  // 12. p_vf_feats (fp16 out)
  gemm16<1, 1, 0><<<dim3(144, 4, 1), 256, 0, stream>>>(
      arr1h, nullptr, 1024, Wpvfh, nullptr, 1024, pvf16, 512, 0, 512, 1024);

  // 13. attention-2 scores
  score_kernel<true, true><<<4608, 256, 0, stream>>>(
      pvf16, atth + 512, bh2att2, b_pvf, Walpha2, balpha2, scores2, 36, 18432);

  // 14. attention-2 softmax + weighted sum -> X2h[:,0:1024]
  attsum2_kernel<<<512, 256, 0, stream>>>(scores2, arr1h, X2h);

  // 15. lang-LSTM gates, plain fp16, K-split z=2 (g2p overlays arr1h region)
  gemm16<1, 0, 0><<<dim3(4, 32, 2), 256, 0, stream>>>(
      X2h, nullptr, 4096, WcLh, nullptr, 4096, g2p, 4096, 2097152, 4096, 2048);

  // 16. lang-LSTM activation -> output
  lstm_act_kernel<false><<<2048, 256, 0, stream>>>(
      g2p, b_ih_lang, b_hh_lang, state_c + 524288, out, out_c1,
      nullptr, nullptr, nullptr, nullptr, out_h1);
}

// Round 3
// 443.817 us; speedup vs baseline: 2.2128x; 1.2910x over previous
//
#include <hip/hip_runtime.h>

typedef __attribute__((ext_vector_type(4))) float f32x4;
typedef __attribute__((ext_vector_type(8))) _Float16 half8;
typedef __attribute__((ext_vector_type(4))) _Float16 half4;

__device__ __forceinline__ float fast_tanh(float x) {
  float e = __expf(2.f * x);
  return 1.f - 2.f / (e + 1.f);
}
__device__ __forceinline__ float fast_sigmoid(float x) {
  return 1.f / (1.f + __expf(-x));
}

__device__ __forceinline__ void gl_lds16(const _Float16* g, _Float16* l) {
  __builtin_amdgcn_global_load_lds(
      (const __attribute__((address_space(1))) void*)g,
      (__attribute__((address_space(3))) void*)l, 16, 0, 0);
}

// ---------------------------------------------------------------------------
// C[M,N] = A[M,K] @ B[N,K]^T, fp16 (hi/lo split optional), f32 accum.
// blockIdx.x = N-tile (fastest -> blocks sharing a W tile land on one XCD),
// blockIdx.y = M-tile, blockIdx.z = K-split (writes partial at z*czstride).
// ---------------------------------------------------------------------------
template<int SPLIT, int OUT16, int NGUARD>
__global__ __launch_bounds__(256) void gemm16(
    const _Float16* __restrict__ Ahp, const _Float16* __restrict__ Alp, int lda,
    const _Float16* __restrict__ Bhp, const _Float16* __restrict__ Blp, int ldb,
    void* __restrict__ Cp, int ldc, long czstride,
    int N, int Kc)
{
  __shared__ _Float16 sAh[128 * 32];
  __shared__ _Float16 sBh[128 * 32];
  __shared__ _Float16 sAl[SPLIT == 3 ? 128 * 32 : 8];
  __shared__ _Float16 sBl[SPLIT == 3 ? 128 * 32 : 8];

  const int tid = threadIdx.x, lane = tid & 63, wid = tid >> 6;
  const int wm = wid >> 1, wn = wid & 1;
  const int l16 = lane & 15, k8 = lane >> 4;
  const int srow = lane >> 2;          // 0..15 within a 16-row chunk
  const int scol = (lane & 3) * 8;     // fp16 col offset (16B granules)

  const int  kt0   = blockIdx.z * Kc;
  const long abase = (long)blockIdx.y * 128;   // M
  const long bbase = (long)blockIdx.x * 128;   // N

  const int r0 = wid * 32 + srow;
  const int r1 = wid * 32 + 16 + srow;
  long br0 = bbase + r0, br1 = bbase + r1;
  if (NGUARD) {
    if (br0 > N - 1) br0 = N - 1;
    if (br1 > N - 1) br1 = N - 1;
  }

  const _Float16* ga0 = Ahp + (abase + r0) * (long)lda + kt0 + scol;
  const _Float16* ga1 = Ahp + (abase + r1) * (long)lda + kt0 + scol;
  const _Float16* gb0 = Bhp + br0 * (long)ldb + kt0 + scol;
  const _Float16* gb1 = Bhp + br1 * (long)ldb + kt0 + scol;
  const _Float16* la0 = SPLIT == 3 ? Alp + (abase + r0) * (long)lda + kt0 + scol : nullptr;
  const _Float16* la1 = SPLIT == 3 ? Alp + (abase + r1) * (long)lda + kt0 + scol : nullptr;
  const _Float16* lb0 = SPLIT == 3 ? Blp + br0 * (long)ldb + kt0 + scol : nullptr;
  const _Float16* lb1 = SPLIT == 3 ? Blp + br1 * (long)ldb + kt0 + scol : nullptr;

  const int e0 = (wid * 32) * 32;
  const int e1 = (wid * 32 + 16) * 32;

  f32x4 acc[4][4];
#pragma unroll
  for (int i = 0; i < 4; i++)
#pragma unroll
    for (int j = 0; j < 4; j++) acc[i][j] = (f32x4){0.f, 0.f, 0.f, 0.f};

  for (int kk = 0; kk < Kc; kk += 32) {
    gl_lds16(ga0 + kk, sAh + e0);
    gl_lds16(ga1 + kk, sAh + e1);
    gl_lds16(gb0 + kk, sBh + e0);
    gl_lds16(gb1 + kk, sBh + e1);
    if (SPLIT == 3) {
      gl_lds16(la0 + kk, sAl + e0);
      gl_lds16(la1 + kk, sAl + e1);
      gl_lds16(lb0 + kk, sBl + e0);
      gl_lds16(lb1 + kk, sBl + e1);
    }
    __syncthreads();

    half8 ah[4], bh[4];
#pragma unroll
    for (int m = 0; m < 4; m++)
      ah[m] = *(const half8*)&sAh[(wm * 64 + m * 16 + l16) * 32 + k8 * 8];
#pragma unroll
    for (int n = 0; n < 4; n++)
      bh[n] = *(const half8*)&sBh[(wn * 64 + n * 16 + l16) * 32 + k8 * 8];
#pragma unroll
    for (int m = 0; m < 4; m++)
#pragma unroll
      for (int n = 0; n < 4; n++)
        acc[m][n] = __builtin_amdgcn_mfma_f32_16x16x32_f16(ah[m], bh[n], acc[m][n], 0, 0, 0);
    if (SPLIT == 3) {
      half8 al[4], bl[4];
#pragma unroll
      for (int m = 0; m < 4; m++)
        al[m] = *(const half8*)&sAl[(wm * 64 + m * 16 + l16) * 32 + k8 * 8];
#pragma unroll
      for (int n = 0; n < 4; n++)
        bl[n] = *(const half8*)&sBl[(wn * 64 + n * 16 + l16) * 32 + k8 * 8];
#pragma unroll
      for (int m = 0; m < 4; m++)
#pragma unroll
        for (int n = 0; n < 4; n++) {
          acc[m][n] = __builtin_amdgcn_mfma_f32_16x16x32_f16(al[m], bh[n], acc[m][n], 0, 0, 0);
          acc[m][n] = __builtin_amdgcn_mfma_f32_16x16x32_f16(ah[m], bl[n], acc[m][n], 0, 0, 0);
        }
    }
    __syncthreads();
  }

  const long czoff = (long)blockIdx.z * czstride;
#pragma unroll
  for (int m = 0; m < 4; m++)
#pragma unroll
    for (int n = 0; n < 4; n++) {
      const long row0 = abase + wm * 64 + m * 16 + (lane >> 4) * 4;
      const long col  = bbase + wn * 64 + n * 16 + l16;
      if (!NGUARD || col < N) {
#pragma unroll
        for (int j = 0; j < 4; j++) {
          if (OUT16) ((_Float16*)Cp)[(row0 + j) * (long)ldc + col + czoff] = (_Float16)acc[m][n][j];
          else       ((float*)Cp)[(row0 + j) * (long)ldc + col + czoff] = acc[m][n][j];
        }
      }
    }
}

// ---------------------------------------------------------------------------
__global__ __launch_bounds__(256) void pack_kernel(
    const float* __restrict__ xt, const float* __restrict__ fc,
    const float* __restrict__ sh,
    _Float16* __restrict__ X1h, _Float16* __restrict__ X1l)
{
  int i = blockIdx.x * 256 + threadIdx.x;   // [0, 512*1024)
  int b = i >> 10, rr = i & 1023;
  long base = (long)b * 4096;
  float v[4];
  v[0] = sh[524288 + i];   // prev_h = state_h[1]
  v[1] = fc[i];
  v[2] = xt[i];
  v[3] = sh[i];            // state_h[0] (hidden)
#pragma unroll
  for (int j = 0; j < 4; j++) {
    _Float16 h = (_Float16)v[j];
    X1h[base + j * 1024 + rr] = h;
    X1l[base + j * 1024 + rr] = (_Float16)(v[j] - (float)h);
  }
}

__global__ __launch_bounds__(256) void convertA_kernel(
    const float* __restrict__ WihA, const float* __restrict__ WhhA,
    const float* __restrict__ Wh1, const float* __restrict__ Wh2,
    const float* __restrict__ Wvf, const float* __restrict__ Wpvf,
    _Float16* __restrict__ WcAh, _Float16* __restrict__ WcAl,
    _Float16* __restrict__ W12h, _Float16* __restrict__ Wvfh,
    _Float16* __restrict__ Wvfl, _Float16* __restrict__ Wpvfh)
{
  int bi = blockIdx.x, t = threadIdx.x;
  if (bi < 16384) {                       // Wc_att [4096][4096] hi+lo
    long e = ((long)bi * 256 + t) * 4;
    int row = (int)(e >> 12), col = (int)(e & 4095);
    const float* src = (col < 3072) ? WihA + (long)row * 3072 + col
                                    : WhhA + (long)row * 1024 + (col - 3072);
    f32x4 v = *(const f32x4*)src;
    half4 h, l;
#pragma unroll
    for (int j = 0; j < 4; j++) { h[j] = (_Float16)v[j]; l[j] = (_Float16)(v[j] - (float)h[j]); }
    *(half4*)&WcAh[e] = h;
    *(half4*)&WcAl[e] = l;
  } else if (bi < 17408) {                // Whh12 [1024][1024]
    long e = ((long)(bi - 16384) * 256 + t) * 4;
    int row = (int)(e >> 10), col = (int)(e & 1023);
    const float* src = (row < 512) ? Wh1 + (long)row * 1024 + col
                                   : Wh2 + (long)(row - 512) * 1024 + col;
    f32x4 v = *(const f32x4*)src;
    half4 h;
#pragma unroll
    for (int j = 0; j < 4; j++) h[j] = (_Float16)v[j];
    *(half4*)&W12h[e] = h;
  } else if (bi < 17800) {                // Wvf [196][2048] hi+lo
    long e = ((long)(bi - 17408) * 256 + t) * 4;
    f32x4 v = *(const f32x4*)(Wvf + e);
    half4 h, l;
#pragma unroll
    for (int j = 0; j < 4; j++) { h[j] = (_Float16)v[j]; l[j] = (_Float16)(v[j] - (float)h[j]); }
    *(half4*)&Wvfh[e] = h;
    *(half4*)&Wvfl[e] = l;
  } else {                                // Wpvf [512][1024]
    long e = ((long)(bi - 17800) * 256 + t) * 4;
    f32x4 v = *(const f32x4*)(Wpvf + e);
    half4 h;
#pragma unroll
    for (int j = 0; j < 4; j++) h[j] = (_Float16)v[j];
    *(half4*)&Wpvfh[e] = h;
  }
}

__global__ __launch_bounds__(256) void convertL_kernel(
    const float* __restrict__ WihL, const float* __restrict__ WhhL,
    _Float16* __restrict__ WcLh)
{
  long e = ((long)blockIdx.x * 256 + threadIdx.x) * 4;
  int row = (int)(e >> 12), col = (int)(e & 4095);
  const float* src = (col < 3072) ? WihL + (long)row * 3072 + col
                                  : WhhL + (long)row * 1024 + (col - 3072);
  f32x4 v = *(const f32x4*)src;
  half4 h;
#pragma unroll
  for (int j = 0; j < 4; j++) h[j] = (_Float16)v[j];
  *(half4*)&WcLh[e] = h;
}

// LSTM activation; sums NP K-split partials (f32 or fp16 per H16).
template<int NP, bool H16, bool ATT>
__global__ __launch_bounds__(256) void lstm_act_kernel(
    const void* __restrict__ gp, const float* __restrict__ bih,
    const float* __restrict__ bhh, const float* __restrict__ cin,
    float* __restrict__ hOut, float* __restrict__ cOut,
    _Float16* __restrict__ hatt_h, _Float16* __restrict__ conch,
    _Float16* __restrict__ concl, float* __restrict__ hOut2)
{
  const long S = 2097152;   // 512*4096
  int i = blockIdx.x * 256 + threadIdx.x;   // [0, 512*1024)
  int b = i >> 10, rr = i & 1023;
  long gb = (long)b * 4096;
  float g4[4];
#pragma unroll
  for (int q = 0; q < 4; q++) {
    float s = 0.f;
#pragma unroll
    for (int z = 0; z < NP; z++) {
      long off = (long)z * S + gb + q * 1024 + rr;
      s += H16 ? (float)((const _Float16*)gp)[off] : ((const float*)gp)[off];
    }
    g4[q] = s + bih[q * 1024 + rr] + bhh[q * 1024 + rr];
  }
  float c  = cin[i];
  float c2 = fast_sigmoid(g4[1]) * c + fast_sigmoid(g4[0]) * fast_tanh(g4[2]);
  float h2 = fast_sigmoid(g4[3]) * fast_tanh(c2);
  hOut[i] = h2;
  cOut[i] = c2;
  if (hOut2) hOut2[i] = h2;
  if (ATT) {
    _Float16 hh = (_Float16)h2;
    hatt_h[i] = hh;
    conch[(long)b * 2048 + 1024 + rr] = hh;
    concl[(long)b * 2048 + 1024 + rr] = (_Float16)(h2 - (float)hh);
  }
}

// fill X2h slots 1024 (h_att) and 3072 (state_h[1]) -- kept out of lstm_act
// because X2h overlays the g1p partial region that lstm_act reads.
__global__ __launch_bounds__(256) void x2fill_kernel(
    const float* __restrict__ hatt, const float* __restrict__ sh,
    _Float16* __restrict__ x2h)
{
  int i = blockIdx.x * 256 + threadIdx.x;   // [0, 512*1024)
  int b = i >> 10, rr = i & 1023;
  x2h[(long)b * 4096 + 1024 + rr] = (_Float16)hatt[i];
  x2h[(long)b * 4096 + 3072 + rr] = (_Float16)sh[524288 + i];
}

__global__ __launch_bounds__(256) void reduce_atth_kernel(
    const float* __restrict__ p, float* __restrict__ o)
{
  int i = (blockIdx.x * 256 + threadIdx.x) * 4;   // 524288 elems, grid 512
  f32x4 a = *(const f32x4*)(p + i);
  f32x4 b = *(const f32x4*)(p + 524288 + i);
  f32x4 c = *(const f32x4*)(p + 1048576 + i);
  f32x4 d = *(const f32x4*)(p + 1572864 + i);
  *(f32x4*)(o + i) = a + b + c + d;
}

template<bool EXTRA, bool PF16>
__global__ __launch_bounds__(256) void score_kernel(
    const void* __restrict__ pf, const float* __restrict__ atth,
    const float* __restrict__ bh, const float* __restrict__ extra,
    const float* __restrict__ walpha, const float* __restrict__ balpha,
    float* __restrict__ out, int S, int nrows)
{
  int gw = blockIdx.x * 4 + (threadIdx.x >> 6);
  int lane = threadIdx.x & 63;
  if (gw >= nrows) return;
  int b = gw / S;
  const float* ah = atth + (long)b * 1024 + lane * 8;
  const float* bp = bh + lane * 8;
  const float* wp = walpha + lane * 8;
  const float* ep = EXTRA ? extra + lane * 8 : nullptr;
  float pv[8];
  if (PF16) {
    half8 hv = *(const half8*)((const _Float16*)pf + (long)gw * 512 + lane * 8);
#pragma unroll
    for (int j = 0; j < 8; j++) pv[j] = (float)hv[j];
  } else {
    const float* p = (const float*)pf + (long)gw * 512 + lane * 8;
#pragma unroll
    for (int u = 0; u < 2; u++) { f32x4 t = *(const f32x4*)(p + u * 4);
#pragma unroll
      for (int j = 0; j < 4; j++) pv[u * 4 + j] = t[j]; }
  }
  float acc = 0.f;
#pragma unroll
  for (int u = 0; u < 2; u++) {
    f32x4 av = *(const f32x4*)(ah + u * 4);
    f32x4 bv = *(const f32x4*)(bp + u * 4);
    f32x4 wv = *(const f32x4*)(wp + u * 4);
    f32x4 ev = EXTRA ? *(const f32x4*)(ep + u * 4) : (f32x4){0.f, 0.f, 0.f, 0.f};
#pragma unroll
    for (int j = 0; j < 4; j++) {
      float x = pv[u * 4 + j] + av[j] + bv[j] + ev[j];
      acc += fast_tanh(x) * wv[j];
    }
  }
#pragma unroll
  for (int off = 32; off; off >>= 1) acc += __shfl_xor(acc, off);
  if (lane == 0) out[gw] = acc + balpha[0];
}

__global__ __launch_bounds__(256) void attsum1_kernel(
    const float* __restrict__ scores, const float* __restrict__ feats,
    _Float16* __restrict__ conch, _Float16* __restrict__ concl, _Float16* __restrict__ x2h)
{
  __shared__ float w[256];
  int b = blockIdx.x, t = threadIdx.x;
  float s0 = (t < 196) ? scores[b * 196 + t] : -3.0e38f;
  w[t] = s0;
  __syncthreads();
  float mx = -3.0e38f;
  for (int i = 0; i < 196; i++) mx = fmaxf(mx, w[i]);
  float sum = 0.f;
  for (int i = 0; i < 196; i++) sum += __expf(w[i] - mx);
  float inv = 1.f / sum;
  __syncthreads();
  if (t < 196) w[t] = __expf(s0 - mx) * inv;
  __syncthreads();
  f32x4 acc = (f32x4){0.f, 0.f, 0.f, 0.f};
  const float* fb = feats + (long)b * 200704 + t * 4;
  for (int s0i = 0; s0i < 192; s0i += 8) {
    f32x4 v[8];
#pragma unroll
    for (int u = 0; u < 8; u++) v[u] = *(const f32x4*)(fb + (long)(s0i + u) * 1024);
#pragma unroll
    for (int u = 0; u < 8; u++) {
      float ws = w[s0i + u];
#pragma unroll
      for (int j = 0; j < 4; j++) acc[j] += ws * v[u][j];
    }
  }
#pragma unroll
  for (int u = 192; u < 196; u++) {
    float ws = w[u];
    f32x4 v = *(const f32x4*)(fb + (long)u * 1024);
#pragma unroll
    for (int j = 0; j < 4; j++) acc[j] += ws * v[j];
  }
  half4 h, l;
#pragma unroll
  for (int j = 0; j < 4; j++) { h[j] = (_Float16)acc[j]; l[j] = (_Float16)(acc[j] - (float)h[j]); }
  *(half4*)&conch[(long)b * 2048 + t * 4] = h;
  *(half4*)&concl[(long)b * 2048 + t * 4] = l;
  *(half4*)&x2h[(long)b * 4096 + 2048 + t * 4] = h;
}

__global__ __launch_bounds__(256) void attsum2_kernel(
    const float* __restrict__ scores, const _Float16* __restrict__ arr1h,
    _Float16* __restrict__ x2h)
{
  __shared__ float w[64];
  int b = blockIdx.x, t = threadIdx.x;
  if (t < 64) w[t] = (t < 36) ? scores[b * 36 + t] : -3.0e38f;
  __syncthreads();
  float mx = -3.0e38f;
  for (int i = 0; i < 36; i++) mx = fmaxf(mx, w[i]);
  float sum = 0.f;
  for (int i = 0; i < 36; i++) sum += __expf(w[i] - mx);
  float inv = 1.f / sum;
  __syncthreads();
  if (t < 36) w[t] = __expf(w[t] - mx) * inv;
  __syncthreads();
  f32x4 acc = (f32x4){0.f, 0.f, 0.f, 0.f};
  const _Float16* fb = arr1h + (long)b * 36 * 1024 + t * 4;
#pragma unroll 4
  for (int s = 0; s < 36; s++) {
    float ws = w[s];
    half4 v = *(const half4*)(fb + (long)s * 1024);
#pragma unroll
    for (int j = 0; j < 4; j++) acc[j] += ws * (float)v[j];
  }
  half4 h;
#pragma unroll
  for (int j = 0; j < 4; j++) h[j] = (_Float16)acc[j];
  *(half4*)&x2h[(long)b * 4096 + t * 4] = h;
}

// one wave per b: top-36 of (sum_z vfhap[z,b,s]) + b_vf[s]  (index set only)
__global__ __launch_bounds__(64) void topk_kernel(
    const float* __restrict__ vfp, const float* __restrict__ b_vf, int* __restrict__ ix)
{
  int b = blockIdx.x;
  int lane = threadIdx.x;
  float v[4];
#pragma unroll
  for (int j = 0; j < 4; j++) {
    int s = lane + 64 * j;
    float sum = -3.0e38f;
    if (s < 196) {
      sum = b_vf[s];
#pragma unroll
      for (int z = 0; z < 8; z++) sum += vfp[(long)z * 100352 + b * 196 + s];
    }
    v[j] = sum;
  }
  for (int it = 0; it < 36; it++) {
    float bv = -3.0e38f; int bs = 1 << 20;
#pragma unroll
    for (int j = 0; j < 4; j++) {
      int s = lane + 64 * j;
      if (v[j] > bv) { bv = v[j]; bs = s; }
    }
#pragma unroll
    for (int off = 32; off; off >>= 1) {
      float ov = __shfl_xor(bv, off);
      int   os = __shfl_xor(bs, off);
      if (ov > bv || (ov == bv && os < bs)) { bv = ov; bs = os; }
    }
    if ((bs & 63) == lane) v[bs >> 6] = -3.0e38f;
    if (lane == 0) ix[b * 36 + it] = bs;
  }
}

__global__ __launch_bounds__(256) void gather_conv_kernel(
    const float* __restrict__ feats, const int* __restrict__ ix, _Float16* __restrict__ dst)
{
  int bj = blockIdx.x;
  int b = bj / 36;
  int s = ix[bj];
  int t = threadIdx.x;
  f32x4 v = *(const f32x4*)(feats + ((long)b * 196 + s) * 1024 + t * 4);
  half4 h;
#pragma unroll
  for (int j = 0; j < 4; j++) h[j] = (_Float16)v[j];
  *(half4*)&dst[(long)bj * 1024 + t * 4] = h;
}

// ---------------------------------------------------------------------------
extern "C" void kernel_launch(void* const* d_in, const int* in_sizes, int n_in,
                              void* d_out, int out_size, void* d_ws, size_t ws_size,
                              hipStream_t stream) {
  const float* xt        = (const float*)d_in[0];
  const float* fc_feats  = (const float*)d_in[1];
  const float* att_feats = (const float*)d_in[2];
  const float* p_att     = (const float*)d_in[3];
  const float* state_h   = (const float*)d_in[4];
  const float* state_c   = (const float*)d_in[5];
  const float* b_ih_att  = (const float*)d_in[7];
  const float* b_hh_att  = (const float*)d_in[9];
  const float* b_ih_lang = (const float*)d_in[11];
  const float* b_hh_lang = (const float*)d_in[13];
  const float* bh2att1   = (const float*)d_in[15];
  const float* Walpha1   = (const float*)d_in[16];
  const float* balpha1   = (const float*)d_in[17];
  const float* bh2att2   = (const float*)d_in[19];
  const float* Walpha2   = (const float*)d_in[20];
  const float* balpha2   = (const float*)d_in[21];
  const float* b_vf      = (const float*)d_in[23];
  const float* b_pvf     = (const float*)d_in[25];

  float* out = (float*)d_out;
  float* W = (float*)d_ws;   // pool, f32-unit offsets

  // --- static regions ---
  _Float16* WcAh   = (_Float16*)(W + 0);         // [4096][4096] hi; later WcLh
  _Float16* WcAl   = (_Float16*)(W + 8388608);   // [4096][4096] lo
  _Float16* X1h    = (_Float16*)(W + 16777216);  // [512][4096]
  _Float16* X1l    = (_Float16*)(W + 17825792);  // [512][4096]
  float*    g1p    = W + 18874368;               // [4][512][4096] f32 (z=4)
  _Float16* hatt_h = (_Float16*)(W + 27262976);  // [512][1024]
  _Float16* W12h   = (_Float16*)(W + 27525120);  // [1024][1024]
  _Float16* Wvfh   = (_Float16*)(W + 28049408);  // [196][2048]
  _Float16* Wvfl   = (_Float16*)(W + 28250112);  // [196][2048]
  _Float16* Wpvfh  = (_Float16*)(W + 28450816);  // [512][1024]  (ws high-water 28712960 f32)
  // --- overlays (producer dead before overlay written) ---
  _Float16* WcLh   = WcAh;                        // lang weights, after att gemm
  float*    vfhap  = W + 8388608;                 // [8][512][196], before arr1h
  _Float16* arr1h  = (_Float16*)(W + 8388608);    // [18432][1024], after topk (ends 17825792)
  _Float16* g2ph   = (_Float16*)(W + 8388608);    // [8][512][4096] fp16, after attsum2
  _Float16* conch  = (_Float16*)(W + 17825792);   // [512][2048] (over dead X1l)
  _Float16* concl  = (_Float16*)(W + 18350080);   // [512][2048]
  int*      vfix   = (int*)(W + 17825792);        // [512*36], after conc dead (topk)
  float*    scores2= W + 17844224;                // [512*36]
  float*    atthp  = W + 18874368;                // [4][512][1024] (inside dead g1p)
  float*    atth   = W + 20971520;                // [512][1024]
  _Float16* X2h    = (_Float16*)(W + 21495808);   // [512][4096]
  float*    scores1= W + 22544384;                // [512*196] (before pvf16)
  _Float16* pvf16  = (_Float16*)(W + 22544384);   // [18432][512], after attsum1 (ends 27262976)

  float* out_h0 = out + 524288;
  float* out_h1 = out + 2 * 524288;
  float* out_c0 = out + 3 * 524288;
  float* out_c1 = out + 4 * 524288;

  // 1. pack X1 hi/lo
  pack_kernel<<<2048, 256, 0, stream>>>(xt, fc_feats, state_h, X1h, X1l);

  // 2. convert all weights except lang
  convertA_kernel<<<18312, 256, 0, stream>>>(
      (const float*)d_in[6], (const float*)d_in[8],
      (const float*)d_in[14], (const float*)d_in[18],
      (const float*)d_in[22], (const float*)d_in[24],
      WcAh, WcAl, W12h, Wvfh, Wvfl, Wpvfh);

  // 3. att-LSTM gates, split-3, z=4 (512 blocks = 2/CU)
  gemm16<3, 0, 0><<<dim3(32, 4, 4), 256, 0, stream>>>(
      X1h, X1l, 4096, WcAh, WcAl, 4096, g1p, 4096, 2097152, 4096, 1024);

  // 4. att-LSTM activation (sums 4 f32 partials)
  lstm_act_kernel<4, false, true><<<2048, 256, 0, stream>>>(
      g1p, b_ih_att, b_hh_att, state_c, out_h0, out_c0,
      hatt_h, conch, concl, nullptr);

  // 5. X2h slots 1024/3072 (separate: X2h overlays g1p)
  x2fill_kernel<<<2048, 256, 0, stream>>>(out_h0, state_h, X2h);

  // 6. convert lang weights (over dead WcAh)
  convertL_kernel<<<16384, 256, 0, stream>>>(
      (const float*)d_in[10], (const float*)d_in[12], WcLh);

  // 7. fused atth1|atth2 projection, z=4 (128 blocks)
  gemm16<1, 0, 0><<<dim3(8, 4, 4), 256, 0, stream>>>(
      hatt_h, nullptr, 1024, W12h, nullptr, 1024, atthp, 1024, 524288, 1024, 256);
  reduce_atth_kernel<<<512, 256, 0, stream>>>(atthp, atth);

  // 8. attention-1 scores
  score_kernel<false, false><<<25088, 256, 0, stream>>>(
      p_att, atth, bh2att1, nullptr, Walpha1, balpha1, scores1, 196, 100352);

  // 9. attention-1 softmax + weighted sum (unroll 8)
  attsum1_kernel<<<512, 256, 0, stream>>>(scores1, att_feats, conch, concl, X2h);

  // 10. vf logits, split-3, z=8 (64 blocks; partials summed in topk)
  gemm16<3, 0, 1><<<dim3(2, 4, 8), 256, 0, stream>>>(
      conch, concl, 2048, Wvfh, Wvfl, 2048, vfhap, 196, 100352, 196, 256);

  // 11. top-36
  topk_kernel<<<512, 64, 0, stream>>>(vfhap, b_vf, vfix);

  // 12. gather + fp16 convert
  gather_conv_kernel<<<18432, 256, 0, stream>>>(att_feats, vfix, arr1h);

  // 13. p_vf_feats (fp16 out)
  gemm16<1, 1, 0><<<dim3(4, 144, 1), 256, 0, stream>>>(
      arr1h, nullptr, 1024, Wpvfh, nullptr, 1024, pvf16, 512, 0, 512, 1024);

  // 14. attention-2 scores
  score_kernel<true, true><<<4608, 256, 0, stream>>>(
      pvf16, atth + 512, bh2att2, b_pvf, Walpha2, balpha2, scores2, 36, 18432);

  // 15. attention-2 softmax + weighted sum -> X2h[:,0:1024]
  attsum2_kernel<<<512, 256, 0, stream>>>(scores2, arr1h, X2h);

  // 16. lang-LSTM gates, z=8 fp16 partials (1024 blocks = 4/CU)
  gemm16<1, 1, 0><<<dim3(32, 4, 8), 256, 0, stream>>>(
      X2h, nullptr, 4096, WcLh, nullptr, 4096, g2ph, 4096, 2097152, 4096, 512);

  // 17. lang-LSTM activation -> output (sums 8 fp16 partials)
  lstm_act_kernel<8, true, false><<<2048, 256, 0, stream>>>(
      g2ph, b_ih_lang, b_hh_lang, state_c + 524288, out, out_c1,
      nullptr, nullptr, nullptr, out_h1);
}